// Round 5
// baseline (559.410 us; speedup 1.0000x reference)
//
#include <hip/hip_runtime.h>
#include <hip/hip_bf16.h>
#include <math.h>

// ---------- types ----------
typedef short short8 __attribute__((ext_vector_type(8)));
typedef ushort ushort8v __attribute__((ext_vector_type(8)));
typedef float floatx4 __attribute__((ext_vector_type(4)));

__device__ __forceinline__ float bf2f(ushort u) {
    union { unsigned int i; float f; } v; v.i = ((unsigned int)u) << 16; return v.f;
}
__device__ __forceinline__ ushort f2bf(float f) {
    union { float f; unsigned int i; } v; v.f = f;
    unsigned int x = v.i;
    unsigned int lsb = (x >> 16) & 1u;
    x += 0x7fffu + lsb;
    return (ushort)(x >> 16);
}
__device__ __forceinline__ float gelu_f(float x) {
    return 0.5f * x * (1.0f + erff(x * 0.7071067811865475f));
}
__device__ __forceinline__ void store4(ushort* p, float a, float b, float c, float d) {
    ushort4 o; o.x = f2bf(a); o.y = f2bf(b); o.z = f2bf(c); o.w = f2bf(d);
    *(ushort4*)p = o;
}
__device__ __forceinline__ void store4(float* p, float a, float b, float c, float d) {
    *(float4*)p = make_float4(a, b, c, d);
}

// ---------- fused fp32 -> bf16 convert (weights only): 6 segments ----------
struct CvtDesc {
    const float* in[6];
    ushort* out[6];
    int nblk[6];
};
__global__ __launch_bounds__(256) void cvt_all_kernel(CvtDesc d) {
    int b = blockIdx.x;
    int s = 0;
    int off = b;
    while (off >= d.nblk[s]) { off -= d.nblk[s]; s++; }
    int i = off * 1024 + threadIdx.x * 4;
    float4 v = *(const float4*)(d.in[s] + i);
    ushort4 o;
    o.x = f2bf(v.x); o.y = f2bf(v.y); o.z = f2bf(v.z); o.w = f2bf(v.w);
    *(ushort4*)(d.out[s] + i) = o;
}

// ---------- A-staging policies ----------
// Each stager fills 8 contiguous bf16 elements of the A LDS tile for
// (global row, global k-offset). DMA variant uses global_load_lds; VALU
// variants compute the A element in-register (fusing a producer kernel).
struct StageDMA {               // plain bf16 matrix in global
    const ushort* A; int lda;
    __device__ __forceinline__ void stage(int row, int kof, ushort* dst) const {
        const ushort* g = A + (size_t)row * lda + kof;
        __builtin_amdgcn_global_load_lds((const __attribute__((address_space(1))) void*)g,
                                         (__attribute__((address_space(3))) void*)dst,
                                         16, 0, 0);
    }
};
struct StageF32 {               // fp32 matrix in global, convert during staging
    const float* A; int lda;
    __device__ __forceinline__ void stage(int row, int kof, ushort* dst) const {
        const float* g = A + (size_t)row * lda + kof;
        float4 f0 = *(const float4*)g;
        float4 f1 = *(const float4*)(g + 4);
        ushort8v u;
        u[0] = f2bf(f0.x); u[1] = f2bf(f0.y); u[2] = f2bf(f0.z); u[3] = f2bf(f0.w);
        u[4] = f2bf(f1.x); u[5] = f2bf(f1.y); u[6] = f2bf(f1.z); u[7] = f2bf(f1.w);
        *(ushort8v*)dst = u;
    }
};
struct StageAttnO {             // A row = attention output O, built from V + weights
    const ushort* qkv;          // [16384, 3072]; V at +2048
    const float4* aw;           // [pair*8+head] = {a00,a01,a10,a11}
    __device__ __forceinline__ void stage(int row, int kof, ushort* dst) const {
        const int p = row >> 1, m = row & 1;
        const int h = kof >> 7, off = kof & 127;
        const ushort* v0 = qkv + (size_t)(p * 2) * 3072 + 2048 + h * 128 + off;
        ushort8v a = *(const ushort8v*)v0;
        ushort8v b = *(const ushort8v*)(v0 + 3072);
        float4 w4 = aw[p * 8 + h];
        float w0 = m ? w4.z : w4.x;
        float w1 = m ? w4.w : w4.y;
        ushort8v u;
#pragma unroll
        for (int k = 0; k < 8; k++) u[k] = f2bf(w0 * bf2f(a[k]) + w1 * bf2f(b[k]));
        *(ushort8v*)dst = u;
    }
};
struct StageGComb {             // A row = g0*c_attn + g1*g_attn (gate combine)
    const ushort* ao;           // [16384, 1024]; rows 2r / 2r+1 = c/g for pair r
    const float* gw;            // [8192, 2] softmax gate weights
    __device__ __forceinline__ void stage(int row, int kof, ushort* dst) const {
        const ushort* c = ao + (size_t)(row * 2) * 1024 + kof;
        ushort8v a = *(const ushort8v*)c;
        ushort8v b = *(const ushort8v*)(c + 1024);
        float g0 = gw[row * 2], g1 = gw[row * 2 + 1];
        ushort8v u;
#pragma unroll
        for (int k = 0; k < 8; k++) u[k] = f2bf(g0 * bf2f(a[k]) + g1 * bf2f(b[k]));
        *(ushort8v*)dst = u;
    }
};

// ---------- GEMM core: C[tile] = act(A[M,K] @ W[N,K]^T + bias) ----------
// 128x128 block tile, BK=64, 256 threads = 4 waves (2x2), each wave 4x4 grid
// of 16x16x32 bf16 MFMA (swapped operands -> packed stores). XOR swizzle on
// k-chunks (bank-conflict-free, verified: SQ_LDS_BANK_CONFLICT=0).
template<int ACT, class StA, typename TOUT>
__device__ __forceinline__ void gemm_core(StA sa,
                                          const ushort* __restrict__ W,
                                          const float* __restrict__ bias,
                                          TOUT* __restrict__ C, int ldc,
                                          int K, int m0, int n0) {
    __shared__ ushort lsA[128 * 64];
    __shared__ ushort lsB[128 * 64];
    const int t = threadIdx.x;
    const int w = t >> 6, l = t & 63;
    const int q = l >> 4, r16 = l & 15;
    const int wm = (w >> 1) * 64, wn = (w & 1) * 64;

    floatx4 acc[4][4];
#pragma unroll
    for (int i = 0; i < 4; i++)
#pragma unroll
        for (int j = 0; j < 4; j++) acc[i][j] = (floatx4){0.f, 0.f, 0.f, 0.f};

    const int srow = t >> 3;          // 0..31: row within a 32-row staging pass
    const int lc   = t & 7;           // chunk slot (8 chunks of 16B per row)
    const int s7 = r16 & 7;
    const int e0 = ((q)     ^ s7) * 8;
    const int e1 = ((q + 4) ^ s7) * 8;

    for (int kt = 0; kt < K; kt += 64) {
        __syncthreads();
#pragma unroll
        for (int rr = 0; rr < 4; ++rr) {
            const int row = rr * 32 + srow;
            const int gc  = (lc ^ (row & 7)) * 8;   // swizzled global k-chunk
            const ushort* gb = W + (size_t)(n0 + row) * K + kt + gc;
            __builtin_amdgcn_global_load_lds((const __attribute__((address_space(1))) void*)gb,
                                             (__attribute__((address_space(3))) void*)&lsB[row * 64 + lc * 8],
                                             16, 0, 0);
            sa.stage(m0 + row, kt + gc, &lsA[row * 64 + lc * 8]);
        }
        __syncthreads();
        {
            short8 af[4], bfr[4];
#pragma unroll
            for (int i = 0; i < 4; i++) af[i]  = *(const short8*)&lsA[(wm + i * 16 + r16) * 64 + e0];
#pragma unroll
            for (int j = 0; j < 4; j++) bfr[j] = *(const short8*)&lsB[(wn + j * 16 + r16) * 64 + e0];
#pragma unroll
            for (int i = 0; i < 4; i++)
#pragma unroll
                for (int j = 0; j < 4; j++)
                    acc[i][j] = __builtin_amdgcn_mfma_f32_16x16x32_bf16(bfr[j], af[i], acc[i][j], 0, 0, 0);
#pragma unroll
            for (int i = 0; i < 4; i++) af[i]  = *(const short8*)&lsA[(wm + i * 16 + r16) * 64 + e1];
#pragma unroll
            for (int j = 0; j < 4; j++) bfr[j] = *(const short8*)&lsB[(wn + j * 16 + r16) * 64 + e1];
#pragma unroll
            for (int i = 0; i < 4; i++)
#pragma unroll
                for (int j = 0; j < 4; j++)
                    acc[i][j] = __builtin_amdgcn_mfma_f32_16x16x32_bf16(bfr[j], af[i], acc[i][j], 0, 0, 0);
        }
    }

    // transposed C-layout: lane holds row = (tile base + r16), cols = j*16 + q*4 + [0..3]
#pragma unroll
    for (int j = 0; j < 4; j++) {
        const int col = n0 + wn + j * 16 + q * 4;
        const float4 bv = *(const float4*)(bias + col);
#pragma unroll
        for (int i = 0; i < 4; i++) {
            const int row = m0 + wm + i * 16 + r16;
            float v0 = acc[i][j][0] + bv.x;
            float v1 = acc[i][j][1] + bv.y;
            float v2 = acc[i][j][2] + bv.z;
            float v3 = acc[i][j][3] + bv.w;
            if (ACT == 1) { v0 = gelu_f(v0); v1 = gelu_f(v1); v2 = gelu_f(v2); v3 = gelu_f(v3); }
            store4(&C[(size_t)row * ldc + col], v0, v1, v2, v3);
        }
    }
}

template<int ACT, int MINW, class StA, typename TOUT>
__global__ __launch_bounds__(256, MINW) void gemm_ker(StA sa,
                                                      const ushort* __restrict__ W,
                                                      const float* __restrict__ bias,
                                                      TOUT* __restrict__ C, int ldc, int K) {
    gemm_core<ACT, StA, TOUT>(sa, W, bias, C, ldc, K, blockIdx.y * 128, blockIdx.x * 128);
}

// both embed GEMMs in one dispatch; A read as fp32 and converted in staging
__global__ __launch_bounds__(256, 3) void embed_gemm(const float* __restrict__ A0,
                                                     const float* __restrict__ A1,
                                                     const ushort* __restrict__ W0,
                                                     const ushort* __restrict__ W1,
                                                     const float* __restrict__ b0,
                                                     const float* __restrict__ b1,
                                                     ushort* __restrict__ C) {
    const int z = blockIdx.z;
    StageF32 sa{z ? A1 : A0, 512};
    gemm_core<0, StageF32, ushort>(sa, z ? W1 : W0, z ? b1 : b0,
                                   C + z * 1024, 2048, 512,
                                   blockIdx.y * 128, blockIdx.x * 128);
}

// ---------- LayerNorm in place over rows of combined (16384 x 1024 bf16) ----------
__global__ __launch_bounds__(256) void ln_kernel(ushort* __restrict__ comb,
                                                 const float* __restrict__ g1, const float* __restrict__ b1,
                                                 const float* __restrict__ g2, const float* __restrict__ b2) {
    int row = blockIdx.x;
    int s = row & 1;
    const float* g = s ? g2 : g1;
    const float* bb = s ? b2 : b1;
    ushort* p = comb + (size_t)row * 1024;
    int t = threadIdx.x;
    ushort4 u = *(const ushort4*)(p + t * 4);
    float x0 = bf2f(u.x), x1 = bf2f(u.y), x2 = bf2f(u.z), x3 = bf2f(u.w);
    float sum = x0 + x1 + x2 + x3;
    float ss = x0 * x0 + x1 * x1 + x2 * x2 + x3 * x3;
#pragma unroll
    for (int off = 32; off; off >>= 1) {
        sum += __shfl_xor(sum, off);
        ss  += __shfl_xor(ss, off);
    }
    __shared__ float sm[8];
    int wv = t >> 6, l = t & 63;
    if (l == 0) { sm[wv * 2] = sum; sm[wv * 2 + 1] = ss; }
    __syncthreads();
    sum = sm[0] + sm[2] + sm[4] + sm[6];
    ss  = sm[1] + sm[3] + sm[5] + sm[7];
    float mean = sum * (1.0f / 1024.0f);
    float var  = ss * (1.0f / 1024.0f) - mean * mean;
    float rstd = rsqrtf(var + 1e-5f);
    float4 gv = *(const float4*)(g + t * 4);
    float4 bv = *(const float4*)(bb + t * 4);
    ushort4 o;
    o.x = f2bf((x0 - mean) * rstd * gv.x + bv.x);
    o.y = f2bf((x1 - mean) * rstd * gv.y + bv.y);
    o.z = f2bf((x2 - mean) * rstd * gv.z + bv.z);
    o.w = f2bf((x3 - mean) * rstd * gv.w + bv.w);
    *(ushort4*)(p + t * 4) = o;
}

// ---------- attention weights: one block per pair; 2x2 softmax per head ----------
// thread t: head h=t>>5, dims (t&31)*4..+3. Reads only Q,K slots of qkv.
// Writes aw[p*8+h] = {a00,a01,a10,a11}. Same fp32 math as the old attn kernel
// -> downstream values bit-identical.
__global__ __launch_bounds__(256) void attn_w_kernel(const ushort* __restrict__ qkv,
                                                     float4* __restrict__ aw) {
    const int p = blockIdx.x;
    const int t = threadIdx.x;
    const int h = t >> 5, d = (t & 31) * 4;
    const ushort* base0 = qkv + (size_t)(p * 2) * 3072 + h * 128 + d;
    const ushort* base1 = base0 + 3072;
    ushort4 uq0 = *(const ushort4*)base0;
    ushort4 uq1 = *(const ushort4*)base1;
    ushort4 uk0 = *(const ushort4*)(base0 + 1024);
    ushort4 uk1 = *(const ushort4*)(base1 + 1024);
    float q0[4] = {bf2f(uq0.x), bf2f(uq0.y), bf2f(uq0.z), bf2f(uq0.w)};
    float q1[4] = {bf2f(uq1.x), bf2f(uq1.y), bf2f(uq1.z), bf2f(uq1.w)};
    float k0[4] = {bf2f(uk0.x), bf2f(uk0.y), bf2f(uk0.z), bf2f(uk0.w)};
    float k1[4] = {bf2f(uk1.x), bf2f(uk1.y), bf2f(uk1.z), bf2f(uk1.w)};
    float p00 = 0.f, p01 = 0.f, p10 = 0.f, p11 = 0.f;
#pragma unroll
    for (int i = 0; i < 4; i++) {
        p00 += q0[i] * k0[i];
        p01 += q0[i] * k1[i];
        p10 += q1[i] * k0[i];
        p11 += q1[i] * k1[i];
    }
#pragma unroll
    for (int off = 16; off; off >>= 1) {
        p00 += __shfl_xor(p00, off);
        p01 += __shfl_xor(p01, off);
        p10 += __shfl_xor(p10, off);
        p11 += __shfl_xor(p11, off);
    }
    const float sc = 0.08838834764831845f;  // 1/sqrt(128)
    p00 *= sc; p01 *= sc; p10 *= sc; p11 *= sc;
    float m0 = fmaxf(p00, p01), m1 = fmaxf(p10, p11);
    float e00 = expf(p00 - m0), e01 = expf(p01 - m0);
    float e10 = expf(p10 - m1), e11 = expf(p11 - m1);
    float i0 = 1.0f / (e00 + e01), i1 = 1.0f / (e10 + e11);
    if ((t & 31) == 0)
        aw[p * 8 + h] = make_float4(e00 * i0, e01 * i0, e10 * i1, e11 * i1);
}

// ---------- gate2 weights: dot over 1024 x2 + softmax -> gw_out only ----------
__global__ __launch_bounds__(256) void gate2w_kernel(const ushort* __restrict__ gate_h,
                                                     const float* __restrict__ w2,
                                                     const float* __restrict__ b2,
                                                     float* __restrict__ gw_out) {
    int b = blockIdx.x;
    int t = threadIdx.x;
    ushort4 u = *(const ushort4*)(gate_h + (size_t)b * 1024 + t * 4);
    float4 w0 = *(const float4*)(w2 + t * 4);
    float4 w1 = *(const float4*)(w2 + 1024 + t * 4);
    float h0 = bf2f(u.x), h1 = bf2f(u.y), h2 = bf2f(u.z), h3 = bf2f(u.w);
    float p0 = h0 * w0.x + h1 * w0.y + h2 * w0.z + h3 * w0.w;
    float p1 = h0 * w1.x + h1 * w1.y + h2 * w1.z + h3 * w1.w;
#pragma unroll
    for (int off = 32; off; off >>= 1) {
        p0 += __shfl_xor(p0, off);
        p1 += __shfl_xor(p1, off);
    }
    __shared__ float sm[8];
    int wv = t >> 6, l = t & 63;
    if (l == 0) { sm[wv * 2] = p0; sm[wv * 2 + 1] = p1; }
    __syncthreads();
    if (t == 0) {
        float d0 = sm[0] + sm[2] + sm[4] + sm[6] + b2[0];
        float d1 = sm[1] + sm[3] + sm[5] + sm[7] + b2[1];
        float mx = fmaxf(d0, d1);
        float e0 = expf(d0 - mx), e1 = expf(d1 - mx);
        float inv = 1.0f / (e0 + e1);
        gw_out[b * 2]     = e0 * inv;
        gw_out[b * 2 + 1] = e1 * inv;
    }
}

// ---------- workspace layout (bytes) ----------
#define OFF_AW     0u          /* attn weights: 8192*8 float4 = 1 MB */
#define OFF_W_CNN  16777216u
#define OFF_W_GNN  17825792u
#define OFF_W_QKV  18874368u
#define OFF_W_AO   25165824u
#define OFF_W_G1   27262976u
#define OFF_W_PJ   31457280u
#define OFF_COMB   33554432u   /* comb (embed->ln->qkv A); later gate_h */
#define OFF_QKV    67108864u   /* 16384x3072 bf16 */
#define OFF_AO     167772160u  /* 16384x1024 bf16 == gate_in (8192 x 2048) */

extern "C" void kernel_launch(void* const* d_in, const int* in_sizes, int n_in,
                              void* d_out, int out_size, void* d_ws, size_t ws_size,
                              hipStream_t stream) {
    const float* cnn_embed  = (const float*)d_in[0];
    const float* gnn_embed  = (const float*)d_in[1];
    const float* cnn_w      = (const float*)d_in[2];
    const float* cnn_b      = (const float*)d_in[3];
    const float* gnn_w      = (const float*)d_in[4];
    const float* gnn_b      = (const float*)d_in[5];
    const float* ln1_g      = (const float*)d_in[6];
    const float* ln1_b      = (const float*)d_in[7];
    const float* ln2_g      = (const float*)d_in[8];
    const float* ln2_b      = (const float*)d_in[9];
    const float* attn_in_w  = (const float*)d_in[10];
    const float* attn_in_b  = (const float*)d_in[11];
    const float* attn_out_w = (const float*)d_in[12];
    const float* attn_out_b = (const float*)d_in[13];
    const float* gate_w1    = (const float*)d_in[14];
    const float* gate_b1    = (const float*)d_in[15];
    const float* gate_w2    = (const float*)d_in[16];
    const float* gate_b2    = (const float*)d_in[17];
    const float* proj_w     = (const float*)d_in[18];
    const float* proj_b     = (const float*)d_in[19];

    char* ws = (char*)d_ws;
    float4* awbuf  = (float4*)(ws + OFF_AW);
    ushort* w_cnn  = (ushort*)(ws + OFF_W_CNN);
    ushort* w_gnn  = (ushort*)(ws + OFF_W_GNN);
    ushort* w_qkv  = (ushort*)(ws + OFF_W_QKV);
    ushort* w_ao   = (ushort*)(ws + OFF_W_AO);
    ushort* w_g1   = (ushort*)(ws + OFF_W_G1);
    ushort* w_pj   = (ushort*)(ws + OFF_W_PJ);
    ushort* comb   = (ushort*)(ws + OFF_COMB);
    ushort* qkv    = (ushort*)(ws + OFF_QKV);
    ushort* ao     = (ushort*)(ws + OFF_AO);
    ushort* gate_h = (ushort*)(ws + OFF_COMB);   // alias: comb dead after qkv GEMM

    float* out_f  = (float*)d_out;
    float* gw_out = out_f + 8192 * 1024;

    // ---- weight fp32 -> bf16 converts in one dispatch ----
    CvtDesc cd;
    cd.in[0] = cnn_w;      cd.out[0] = w_cnn; cd.nblk[0] = 512;
    cd.in[1] = gnn_w;      cd.out[1] = w_gnn; cd.nblk[1] = 512;
    cd.in[2] = attn_in_w;  cd.out[2] = w_qkv; cd.nblk[2] = 3072;
    cd.in[3] = attn_out_w; cd.out[3] = w_ao;  cd.nblk[3] = 1024;
    cd.in[4] = gate_w1;    cd.out[4] = w_g1;  cd.nblk[4] = 2048;
    cd.in[5] = proj_w;     cd.out[5] = w_pj;  cd.nblk[5] = 1024;
    cvt_all_kernel<<<8192, 256, 0, stream>>>(cd);

    dim3 blk(256);

    // ---- both embed GEMMs (fp32 A converted in staging) -> combined (B,2,F) ----
    dim3 g_embed(1024 / 128, 8192 / 128, 2);
    embed_gemm<<<g_embed, blk, 0, stream>>>(cnn_embed, gnn_embed, w_cnn, w_gnn, cnn_b, gnn_b, comb);

    // ---- LayerNorm in place ----
    ln_kernel<<<16384, blk, 0, stream>>>(comb, ln1_g, ln1_b, ln2_g, ln2_b);

    // ---- qkv GEMM ----
    dim3 g_qkv(3072 / 128, 16384 / 128);
    gemm_ker<0, 4, StageDMA, ushort><<<g_qkv, blk, 0, stream>>>(
        StageDMA{comb, 1024}, w_qkv, attn_in_b, qkv, 3072, 1024);

    // ---- attention softmax weights (Q,K only) ----
    attn_w_kernel<<<8192, blk, 0, stream>>>(qkv, awbuf);

    // ---- attn_out GEMM; A = O built on the fly from V + weights ----
    dim3 g_ao(1024 / 128, 16384 / 128);
    gemm_ker<0, 3, StageAttnO, ushort><<<g_ao, blk, 0, stream>>>(
        StageAttnO{qkv, awbuf}, w_ao, attn_out_b, ao, 1024, 1024);

    // ---- gate1 GEMM (gelu); A = ao viewed [8192, 2048] ----
    dim3 g_g1(1024 / 128, 8192 / 128);
    gemm_ker<1, 4, StageDMA, ushort><<<g_g1, blk, 0, stream>>>(
        StageDMA{ao, 2048}, w_g1, gate_b1, gate_h, 1024, 2048);

    // ---- gate2: softmax weights only ----
    gate2w_kernel<<<8192, blk, 0, stream>>>(gate_h, gate_w2, gate_b2, gw_out);

    // ---- proj GEMM (gelu); A = gate-combined rows built in staging ----
    dim3 g_pj(1024 / 128, 8192 / 128);
    gemm_ker<1, 3, StageGComb, float><<<g_pj, blk, 0, stream>>>(
        StageGComb{ao, gw_out}, w_pj, proj_b, out_f, 1024, 1024);
}

// Round 6
// 501.306 us; speedup vs baseline: 1.1159x; 1.1159x over previous
//
#include <hip/hip_runtime.h>
#include <hip/hip_bf16.h>
#include <math.h>

// ---------- types ----------
typedef short short8 __attribute__((ext_vector_type(8)));
typedef ushort ushort8v __attribute__((ext_vector_type(8)));
typedef float floatx16 __attribute__((ext_vector_type(16)));

__device__ __forceinline__ float bf2f(ushort u) {
    union { unsigned int i; float f; } v; v.i = ((unsigned int)u) << 16; return v.f;
}
__device__ __forceinline__ ushort f2bf(float f) {
    union { float f; unsigned int i; } v; v.f = f;
    unsigned int x = v.i;
    unsigned int lsb = (x >> 16) & 1u;
    x += 0x7fffu + lsb;
    return (ushort)(x >> 16);
}
__device__ __forceinline__ float gelu_f(float x) {
    return 0.5f * x * (1.0f + erff(x * 0.7071067811865475f));
}
__device__ __forceinline__ void store4(ushort* p, float a, float b, float c, float d) {
    ushort4 o; o.x = f2bf(a); o.y = f2bf(b); o.z = f2bf(c); o.w = f2bf(d);
    *(ushort4*)p = o;
}
__device__ __forceinline__ void store4(float* p, float a, float b, float c, float d) {
    *(float4*)p = make_float4(a, b, c, d);
}

// ---------- fused fp32 -> bf16 convert (weights only): 6 segments ----------
struct CvtDesc {
    const float* in[6];
    ushort* out[6];
    int nblk[6];
};
__global__ __launch_bounds__(256) void cvt_all_kernel(CvtDesc d) {
    int b = blockIdx.x;
    int s = 0;
    int off = b;
    while (off >= d.nblk[s]) { off -= d.nblk[s]; s++; }
    int i = off * 1024 + threadIdx.x * 4;
    float4 v = *(const float4*)(d.in[s] + i);
    ushort4 o;
    o.x = f2bf(v.x); o.y = f2bf(v.y); o.z = f2bf(v.z); o.w = f2bf(v.w);
    *(ushort4*)(d.out[s] + i) = o;
}

// ---------- GEMM core: C[tile] = act(A[M,K] @ W[N,K]^T + bias) ----------
// 128x128 block tile, BK=64, 256 threads = 4 waves (2x2). Each wave: 2x2 grid
// of 32x32x16 bf16 MFMA (17% fewer MFMA-pipe cycles + half the issue slots of
// 16x16x32 at equal FLOPs; m119: 2495 vs 2075 TF ceiling). Swapped operands
// (mfma(b,a)) -> each lane owns act-row lane&31, packed 8B/16B stores.
// XOR swizzle on 16B k-chunks: global chunk c of row r stored at LDS chunk
// c^(r&7). Read side: 8 dwords/bank per wave access (verified even).
// R3/R4 measured SQ_LDS_BANK_CONFLICT = 0 with this scheme.
// A-staging lesson (R5): DMA-only for A; VALU staging only for coalesced 1:1
// fp32 conversion (embed). Never fuse scattered/2:1 reads into staging.
template<int ACT, int AF32, typename TOUT>
__device__ __forceinline__ void gemm_core(const void* __restrict__ Av, int lda,
                                          const ushort* __restrict__ W,
                                          const float* __restrict__ bias,
                                          TOUT* __restrict__ C, int ldc,
                                          int K, int m0, int n0) {
    __shared__ ushort lsA[128 * 64];
    __shared__ ushort lsB[128 * 64];
    const int t = threadIdx.x;
    const int w = t >> 6, l = t & 63;
    const int r32 = l & 31, h = l >> 5;          // act/W row within tile; k-half
    const int wm = (w >> 1) * 64, wn = (w & 1) * 64;

    floatx16 acc[2][2];
#pragma unroll
    for (int i = 0; i < 2; i++)
#pragma unroll
        for (int j = 0; j < 2; j++)
#pragma unroll
            for (int e = 0; e < 16; e++) acc[i][j][e] = 0.f;

    const int srow = t >> 3;          // 0..31: row within a 32-row staging pass
    const int lc   = t & 7;           // chunk slot (8 chunks of 16B per row)
    const int s7   = r32 & 7;
    // element offset of k-step s's chunk for this lane (swizzled)
    int eoff[4];
#pragma unroll
    for (int s = 0; s < 4; s++) eoff[s] = ((2 * s + h) ^ s7) * 8;

    for (int kt = 0; kt < K; kt += 64) {
        __syncthreads();
#pragma unroll
        for (int rr = 0; rr < 4; ++rr) {
            const int row = rr * 32 + srow;
            const int gc  = (lc ^ (row & 7)) * 8;   // swizzled global k-chunk
            const ushort* gb = W + (size_t)(n0 + row) * K + kt + gc;
            __builtin_amdgcn_global_load_lds((const __attribute__((address_space(1))) void*)gb,
                                             (__attribute__((address_space(3))) void*)&lsB[row * 64 + lc * 8],
                                             16, 0, 0);
            if (!AF32) {
                const ushort* ga = (const ushort*)Av + (size_t)(m0 + row) * lda + kt + gc;
                __builtin_amdgcn_global_load_lds((const __attribute__((address_space(1))) void*)ga,
                                                 (__attribute__((address_space(3))) void*)&lsA[row * 64 + lc * 8],
                                                 16, 0, 0);
            } else {
                const float* ga = (const float*)Av + (size_t)(m0 + row) * lda + kt + gc;
                float4 f0 = *(const float4*)ga;
                float4 f1 = *(const float4*)(ga + 4);
                ushort8v u;
                u[0] = f2bf(f0.x); u[1] = f2bf(f0.y); u[2] = f2bf(f0.z); u[3] = f2bf(f0.w);
                u[4] = f2bf(f1.x); u[5] = f2bf(f1.y); u[6] = f2bf(f1.z); u[7] = f2bf(f1.w);
                *(ushort8v*)&lsA[row * 64 + lc * 8] = u;
            }
        }
        __syncthreads();
#pragma unroll
        for (int s = 0; s < 4; s++) {
            short8 a0 = *(const short8*)&lsA[(wm +      r32) * 64 + eoff[s]];
            short8 a1 = *(const short8*)&lsA[(wm + 32 + r32) * 64 + eoff[s]];
            short8 b0 = *(const short8*)&lsB[(wn +      r32) * 64 + eoff[s]];
            short8 b1 = *(const short8*)&lsB[(wn + 32 + r32) * 64 + eoff[s]];
            acc[0][0] = __builtin_amdgcn_mfma_f32_32x32x16_bf16(b0, a0, acc[0][0], 0, 0, 0);
            acc[0][1] = __builtin_amdgcn_mfma_f32_32x32x16_bf16(b1, a0, acc[0][1], 0, 0, 0);
            acc[1][0] = __builtin_amdgcn_mfma_f32_32x32x16_bf16(b0, a1, acc[1][0], 0, 0, 0);
            acc[1][1] = __builtin_amdgcn_mfma_f32_32x32x16_bf16(b1, a1, acc[1][1], 0, 0, 0);
        }
    }

    // swapped 32x32 C-layout: lane -> act row = tile_base + r32;
    // cols (per reg r=4g+c): j*32 + 8g + 4h + c  -> 4 consecutive cols per group
#pragma unroll
    for (int j = 0; j < 2; j++) {
#pragma unroll
        for (int g = 0; g < 4; g++) {
            const int col = n0 + wn + j * 32 + g * 8 + h * 4;
            const float4 bv = *(const float4*)(bias + col);
#pragma unroll
            for (int i = 0; i < 2; i++) {
                const int row = m0 + wm + i * 32 + r32;
                float v0 = acc[i][j][g * 4 + 0] + bv.x;
                float v1 = acc[i][j][g * 4 + 1] + bv.y;
                float v2 = acc[i][j][g * 4 + 2] + bv.z;
                float v3 = acc[i][j][g * 4 + 3] + bv.w;
                if (ACT == 1) { v0 = gelu_f(v0); v1 = gelu_f(v1); v2 = gelu_f(v2); v3 = gelu_f(v3); }
                store4(&C[(size_t)row * ldc + col], v0, v1, v2, v3);
            }
        }
    }
}

template<int ACT, typename TOUT>
__global__ __launch_bounds__(256, 3) void gemm_bt(const ushort* __restrict__ A, int lda,
                                                  const ushort* __restrict__ W,
                                                  const float* __restrict__ bias,
                                                  TOUT* __restrict__ C, int ldc, int K) {
    gemm_core<ACT, 0, TOUT>(A, lda, W, bias, C, ldc, K, blockIdx.y * 128, blockIdx.x * 128);
}

// both embed GEMMs in one dispatch; A read as fp32 and converted in staging
__global__ __launch_bounds__(256, 3) void embed_gemm(const float* __restrict__ A0,
                                                     const float* __restrict__ A1,
                                                     const ushort* __restrict__ W0,
                                                     const ushort* __restrict__ W1,
                                                     const float* __restrict__ b0,
                                                     const float* __restrict__ b1,
                                                     ushort* __restrict__ C) {
    const int z = blockIdx.z;
    gemm_core<0, 1, ushort>(z ? (const void*)A1 : (const void*)A0, 512,
                            z ? W1 : W0, z ? b1 : b0,
                            C + z * 1024, 2048, 512,
                            blockIdx.y * 128, blockIdx.x * 128);
}

// ---------- LayerNorm in place over rows of combined (16384 x 1024 bf16) ----------
__global__ __launch_bounds__(256) void ln_kernel(ushort* __restrict__ comb,
                                                 const float* __restrict__ g1, const float* __restrict__ b1,
                                                 const float* __restrict__ g2, const float* __restrict__ b2) {
    int row = blockIdx.x;
    int s = row & 1;
    const float* g = s ? g2 : g1;
    const float* bb = s ? b2 : b1;
    ushort* p = comb + (size_t)row * 1024;
    int t = threadIdx.x;
    ushort4 u = *(const ushort4*)(p + t * 4);
    float x0 = bf2f(u.x), x1 = bf2f(u.y), x2 = bf2f(u.z), x3 = bf2f(u.w);
    float sum = x0 + x1 + x2 + x3;
    float ss = x0 * x0 + x1 * x1 + x2 * x2 + x3 * x3;
#pragma unroll
    for (int off = 32; off; off >>= 1) {
        sum += __shfl_xor(sum, off);
        ss  += __shfl_xor(ss, off);
    }
    __shared__ float sm[8];
    int wv = t >> 6, l = t & 63;
    if (l == 0) { sm[wv * 2] = sum; sm[wv * 2 + 1] = ss; }
    __syncthreads();
    sum = sm[0] + sm[2] + sm[4] + sm[6];
    ss  = sm[1] + sm[3] + sm[5] + sm[7];
    float mean = sum * (1.0f / 1024.0f);
    float var  = ss * (1.0f / 1024.0f) - mean * mean;
    float rstd = rsqrtf(var + 1e-5f);
    float4 gv = *(const float4*)(g + t * 4);
    float4 bv = *(const float4*)(bb + t * 4);
    ushort4 o;
    o.x = f2bf((x0 - mean) * rstd * gv.x + bv.x);
    o.y = f2bf((x1 - mean) * rstd * gv.y + bv.y);
    o.z = f2bf((x2 - mean) * rstd * gv.z + bv.z);
    o.w = f2bf((x3 - mean) * rstd * gv.w + bv.w);
    *(ushort4*)(p + t * 4) = o;
}

// ---------- attention v2 (R4): one block per pair; LDS-staged; compact O ----------
__global__ __launch_bounds__(256) void attn_kernel(const ushort* __restrict__ qkv,
                                                   ushort* __restrict__ O) {
    __shared__ ushort ls[6144];
    const int b = blockIdx.x;
    const int t = threadIdx.x;
    const ushort* src = qkv + (size_t)b * 6144;
#pragma unroll
    for (int p = 0; p < 3; ++p) {
        int idx = (p * 256 + t) * 8;
        *(ushort8v*)&ls[idx] = *(const ushort8v*)&src[idx];
    }
    __syncthreads();
    const int h = t >> 5, d32 = t & 31;
    const int o0 = h * 128 + d32 * 4;
    ushort4 uq0 = *(const ushort4*)&ls[o0];
    ushort4 uq1 = *(const ushort4*)&ls[3072 + o0];
    ushort4 uk0 = *(const ushort4*)&ls[1024 + o0];
    ushort4 uk1 = *(const ushort4*)&ls[4096 + o0];
    ushort4 uv0 = *(const ushort4*)&ls[2048 + o0];
    ushort4 uv1 = *(const ushort4*)&ls[5120 + o0];
    float q0[4] = {bf2f(uq0.x), bf2f(uq0.y), bf2f(uq0.z), bf2f(uq0.w)};
    float q1[4] = {bf2f(uq1.x), bf2f(uq1.y), bf2f(uq1.z), bf2f(uq1.w)};
    float k0[4] = {bf2f(uk0.x), bf2f(uk0.y), bf2f(uk0.z), bf2f(uk0.w)};
    float k1[4] = {bf2f(uk1.x), bf2f(uk1.y), bf2f(uk1.z), bf2f(uk1.w)};
    float v0[4] = {bf2f(uv0.x), bf2f(uv0.y), bf2f(uv0.z), bf2f(uv0.w)};
    float v1[4] = {bf2f(uv1.x), bf2f(uv1.y), bf2f(uv1.z), bf2f(uv1.w)};
    float p00 = 0.f, p01 = 0.f, p10 = 0.f, p11 = 0.f;
#pragma unroll
    for (int i = 0; i < 4; i++) {
        p00 += q0[i] * k0[i];
        p01 += q0[i] * k1[i];
        p10 += q1[i] * k0[i];
        p11 += q1[i] * k1[i];
    }
#pragma unroll
    for (int off = 16; off; off >>= 1) {
        p00 += __shfl_xor(p00, off);
        p01 += __shfl_xor(p01, off);
        p10 += __shfl_xor(p10, off);
        p11 += __shfl_xor(p11, off);
    }
    const float sc = 0.08838834764831845f;  // 1/sqrt(128)
    p00 *= sc; p01 *= sc; p10 *= sc; p11 *= sc;
    float m0 = fmaxf(p00, p01), m1 = fmaxf(p10, p11);
    float e00 = expf(p00 - m0), e01 = expf(p01 - m0);
    float e10 = expf(p10 - m1), e11 = expf(p11 - m1);
    float i0 = 1.0f / (e00 + e01), i1 = 1.0f / (e10 + e11);
    float a00 = e00 * i0, a01 = e01 * i0;
    float a10 = e10 * i1, a11 = e11 * i1;
    ushort* dst0 = O + (size_t)(b * 2) * 1024 + o0;
    ushort* dst1 = dst0 + 1024;
    store4(dst0, a00 * v0[0] + a01 * v1[0], a00 * v0[1] + a01 * v1[1],
                 a00 * v0[2] + a01 * v1[2], a00 * v0[3] + a01 * v1[3]);
    store4(dst1, a10 * v0[0] + a11 * v1[0], a10 * v0[1] + a11 * v1[1],
                 a10 * v0[2] + a11 * v1[2], a10 * v0[3] + a11 * v1[3]);
}

// ---------- gate2 (dot over 1024 x2) + softmax + fused combine ----------
__global__ __launch_bounds__(256) void gate2_kernel(const ushort* __restrict__ gate_h,
                                                    const float* __restrict__ w2, const float* __restrict__ b2,
                                                    const ushort* __restrict__ attn_out,
                                                    ushort* __restrict__ fused_pre,
                                                    float* __restrict__ gw_out) {
    int b = blockIdx.x;
    int t = threadIdx.x;
    const ushort* hp = gate_h + (size_t)b * 1024;
    ushort4 u = *(const ushort4*)(hp + t * 4);
    float4 w0 = *(const float4*)(w2 + t * 4);
    float4 w1 = *(const float4*)(w2 + 1024 + t * 4);
    float h0 = bf2f(u.x), h1 = bf2f(u.y), h2 = bf2f(u.z), h3 = bf2f(u.w);
    float p0 = h0 * w0.x + h1 * w0.y + h2 * w0.z + h3 * w0.w;
    float p1 = h0 * w1.x + h1 * w1.y + h2 * w1.z + h3 * w1.w;
#pragma unroll
    for (int off = 32; off; off >>= 1) {
        p0 += __shfl_xor(p0, off);
        p1 += __shfl_xor(p1, off);
    }
    __shared__ float sm[8];
    __shared__ float sgw[2];
    int wv = t >> 6, l = t & 63;
    if (l == 0) { sm[wv * 2] = p0; sm[wv * 2 + 1] = p1; }
    __syncthreads();
    if (t == 0) {
        float d0 = sm[0] + sm[2] + sm[4] + sm[6] + b2[0];
        float d1 = sm[1] + sm[3] + sm[5] + sm[7] + b2[1];
        float mx = fmaxf(d0, d1);
        float e0 = expf(d0 - mx), e1 = expf(d1 - mx);
        float inv = 1.0f / (e0 + e1);
        sgw[0] = e0 * inv; sgw[1] = e1 * inv;
        gw_out[b * 2] = e0 * inv;
        gw_out[b * 2 + 1] = e1 * inv;
    }
    __syncthreads();
    float g0 = sgw[0], g1 = sgw[1];
    const ushort* ca = attn_out + (size_t)b * 2048;
    ushort* fp = fused_pre + (size_t)b * 1024;
    ushort4 uc = *(const ushort4*)(ca + t * 4);
    ushort4 ug = *(const ushort4*)(ca + 1024 + t * 4);
    ushort4 o;
    o.x = f2bf(g0 * bf2f(uc.x) + g1 * bf2f(ug.x));
    o.y = f2bf(g0 * bf2f(uc.y) + g1 * bf2f(ug.y));
    o.z = f2bf(g0 * bf2f(uc.z) + g1 * bf2f(ug.z));
    o.w = f2bf(g0 * bf2f(uc.w) + g1 * bf2f(ug.w));
    *(ushort4*)(fp + t * 4) = o;
}

// ---------- workspace layout (bytes) ----------
// OFF_COMB region is time-multiplexed: comb -> O -> gate_h / fused_pre
#define OFF_W_CNN  16777216u
#define OFF_W_GNN  17825792u
#define OFF_W_QKV  18874368u
#define OFF_W_AO   25165824u
#define OFF_W_G1   27262976u
#define OFF_W_PJ   31457280u
#define OFF_COMB   33554432u
#define OFF_QKV    67108864u   /* 16384x3072 bf16 */
#define OFF_AO     167772160u  /* 16384x1024 bf16 == gate_in (8192 x 2048) */

extern "C" void kernel_launch(void* const* d_in, const int* in_sizes, int n_in,
                              void* d_out, int out_size, void* d_ws, size_t ws_size,
                              hipStream_t stream) {
    const float* cnn_embed  = (const float*)d_in[0];
    const float* gnn_embed  = (const float*)d_in[1];
    const float* cnn_w      = (const float*)d_in[2];
    const float* cnn_b      = (const float*)d_in[3];
    const float* gnn_w      = (const float*)d_in[4];
    const float* gnn_b      = (const float*)d_in[5];
    const float* ln1_g      = (const float*)d_in[6];
    const float* ln1_b      = (const float*)d_in[7];
    const float* ln2_g      = (const float*)d_in[8];
    const float* ln2_b      = (const float*)d_in[9];
    const float* attn_in_w  = (const float*)d_in[10];
    const float* attn_in_b  = (const float*)d_in[11];
    const float* attn_out_w = (const float*)d_in[12];
    const float* attn_out_b = (const float*)d_in[13];
    const float* gate_w1    = (const float*)d_in[14];
    const float* gate_b1    = (const float*)d_in[15];
    const float* gate_w2    = (const float*)d_in[16];
    const float* gate_b2    = (const float*)d_in[17];
    const float* proj_w     = (const float*)d_in[18];
    const float* proj_b     = (const float*)d_in[19];

    char* ws = (char*)d_ws;
    ushort* w_cnn  = (ushort*)(ws + OFF_W_CNN);
    ushort* w_gnn  = (ushort*)(ws + OFF_W_GNN);
    ushort* w_qkv  = (ushort*)(ws + OFF_W_QKV);
    ushort* w_ao   = (ushort*)(ws + OFF_W_AO);
    ushort* w_g1   = (ushort*)(ws + OFF_W_G1);
    ushort* w_pj   = (ushort*)(ws + OFF_W_PJ);
    ushort* comb   = (ushort*)(ws + OFF_COMB);
    ushort* qkv    = (ushort*)(ws + OFF_QKV);
    ushort* ao     = (ushort*)(ws + OFF_AO);
    ushort* Obuf      = (ushort*)(ws + OFF_COMB);              // alias: comb dead after qkv GEMM
    ushort* gate_h    = (ushort*)(ws + OFF_COMB);              // alias: O dead after attn_out GEMM
    ushort* fused_pre = (ushort*)(ws + OFF_COMB + 16777216u);

    float* out_f  = (float*)d_out;
    float* gw_out = out_f + 8192 * 1024;

    // ---- weight fp32 -> bf16 converts in one dispatch ----
    CvtDesc cd;
    cd.in[0] = cnn_w;      cd.out[0] = w_cnn; cd.nblk[0] = 512;
    cd.in[1] = gnn_w;      cd.out[1] = w_gnn; cd.nblk[1] = 512;
    cd.in[2] = attn_in_w;  cd.out[2] = w_qkv; cd.nblk[2] = 3072;
    cd.in[3] = attn_out_w; cd.out[3] = w_ao;  cd.nblk[3] = 1024;
    cd.in[4] = gate_w1;    cd.out[4] = w_g1;  cd.nblk[4] = 2048;
    cd.in[5] = proj_w;     cd.out[5] = w_pj;  cd.nblk[5] = 1024;
    cvt_all_kernel<<<8192, 256, 0, stream>>>(cd);

    dim3 blk(256);

    // ---- both embed GEMMs (fp32 A converted in staging) -> combined (B,2,F) ----
    dim3 g_embed(1024 / 128, 8192 / 128, 2);
    embed_gemm<<<g_embed, blk, 0, stream>>>(cnn_embed, gnn_embed, w_cnn, w_gnn, cnn_b, gnn_b, comb);

    // ---- LayerNorm in place ----
    ln_kernel<<<16384, blk, 0, stream>>>(comb, ln1_g, ln1_b, ln2_g, ln2_b);

    // ---- qkv GEMM ----
    dim3 g_qkv(3072 / 128, 16384 / 128);
    gemm_bt<0, ushort><<<g_qkv, blk, 0, stream>>>(comb, 1024, w_qkv, attn_in_b, qkv, 3072, 1024);

    // ---- attention -> compact O ----
    attn_kernel<<<8192, blk, 0, stream>>>(qkv, Obuf);

    // ---- attn_out GEMM (A = compact O) ----
    dim3 g_ao(1024 / 128, 16384 / 128);
    gemm_bt<0, ushort><<<g_ao, blk, 0, stream>>>(Obuf, 1024, w_ao, attn_out_b, ao, 1024, 1024);

    // ---- gate1 GEMM (gelu) ----
    dim3 g_g1(1024 / 128, 8192 / 128);
    gemm_bt<1, ushort><<<g_g1, blk, 0, stream>>>(ao, 2048, w_g1, gate_b1, gate_h, 1024, 2048);

    // ---- gate2 + softmax + fused combine ----
    gate2_kernel<<<8192, blk, 0, stream>>>(gate_h, gate_w2, gate_b2, ao, fused_pre, gw_out);

    // ---- proj GEMM (gelu) -> out ----
    dim3 g_pj(1024 / 128, 8192 / 128);
    gemm_bt<1, float><<<g_pj, blk, 0, stream>>>(fused_pre, 1024, w_pj, proj_b, out_f, 1024, 1024);
}

// Round 7
// 466.628 us; speedup vs baseline: 1.1988x; 1.0743x over previous
//
#include <hip/hip_runtime.h>
#include <hip/hip_bf16.h>
#include <math.h>

// ---------- types ----------
typedef short short8 __attribute__((ext_vector_type(8)));
typedef ushort ushort8v __attribute__((ext_vector_type(8)));
typedef float floatx4 __attribute__((ext_vector_type(4)));

__device__ __forceinline__ float bf2f(ushort u) {
    union { unsigned int i; float f; } v; v.i = ((unsigned int)u) << 16; return v.f;
}
__device__ __forceinline__ ushort f2bf(float f) {
    union { float f; unsigned int i; } v; v.f = f;
    unsigned int x = v.i;
    unsigned int lsb = (x >> 16) & 1u;
    x += 0x7fffu + lsb;
    return (ushort)(x >> 16);
}
__device__ __forceinline__ float gelu_f(float x) {
    return 0.5f * x * (1.0f + erff(x * 0.7071067811865475f));
}
__device__ __forceinline__ void store4(ushort* p, float a, float b, float c, float d) {
    ushort4 o; o.x = f2bf(a); o.y = f2bf(b); o.z = f2bf(c); o.w = f2bf(d);
    *(ushort4*)p = o;
}
__device__ __forceinline__ void store4(float* p, float a, float b, float c, float d) {
    *(float4*)p = make_float4(a, b, c, d);
}

// XCD-aware swizzle: flat id -> (x=N-tile, y=M-tile). Under round-robin
// dispatch, xcd = id%8; give each XCD a contiguous M-band (bh = ny/8 rows)
// walked column-major so its concurrent A footprint stays L2-resident.
__device__ __forceinline__ int2 swz_xy(int id, int bh) {
    int xcd = id & 7;
    int s = id >> 3;
    int x = s / bh;
    int ry = s - x * bh;
    return make_int2(x, xcd * bh + ry);
}

// ---------- fused fp32 -> bf16 convert (weights only): 6 segments ----------
struct CvtDesc {
    const float* in[6];
    ushort* out[6];
    int nblk[6];
};
__global__ __launch_bounds__(256) void cvt_all_kernel(CvtDesc d) {
    int b = blockIdx.x;
    int s = 0;
    int off = b;
    while (off >= d.nblk[s]) { off -= d.nblk[s]; s++; }
    int i = off * 1024 + threadIdx.x * 4;
    float4 v = *(const float4*)(d.in[s] + i);
    ushort4 o;
    o.x = f2bf(v.x); o.y = f2bf(v.y); o.z = f2bf(v.z); o.w = f2bf(v.w);
    *(ushort4*)(d.out[s] + i) = o;
}

// ---------- GEMM core (R4-verified): C = act(A[M,K] @ W[N,K]^T + bias) ----------
// 128x128 block tile, BK=64, 256 threads = 4 waves (2x2), each wave 4x4 grid
// of 16x16x32 bf16 MFMA, swapped operands (mfma(b,a)) -> packed stores.
// XOR swizzle on 16B k-chunks: SQ_LDS_BANK_CONFLICT = 0 (R3/R4/R5 measured).
// NOTE (R6): the 32x32x16 core regressed (+4 conflict-cyc/ds_read) — keep 16x16.
// NOTE (R5): A-staging must be DMA or coalesced-1:1 VALU (fp32 cvt) only.
template<int ACT, int AF32, typename TOUT>
__device__ __forceinline__ void gemm_core(const void* __restrict__ Av, int lda,
                                          const ushort* __restrict__ W,
                                          const float* __restrict__ bias,
                                          TOUT* __restrict__ C, int ldc,
                                          int K, int m0, int n0) {
    __shared__ ushort lsA[128 * 64];
    __shared__ ushort lsB[128 * 64];
    const int t = threadIdx.x;
    const int w = t >> 6, l = t & 63;
    const int q = l >> 4, r16 = l & 15;
    const int wm = (w >> 1) * 64, wn = (w & 1) * 64;

    floatx4 acc[4][4];
#pragma unroll
    for (int i = 0; i < 4; i++)
#pragma unroll
        for (int j = 0; j < 4; j++) acc[i][j] = (floatx4){0.f, 0.f, 0.f, 0.f};

    const int srow = t >> 3;          // 0..31: row within a 32-row staging pass
    const int lc   = t & 7;           // chunk slot (8 chunks of 16B per row)
    const int s7 = r16 & 7;
    const int e0 = ((q)     ^ s7) * 8;
    const int e1 = ((q + 4) ^ s7) * 8;

    for (int kt = 0; kt < K; kt += 64) {
        __syncthreads();
#pragma unroll
        for (int rr = 0; rr < 4; ++rr) {
            const int row = rr * 32 + srow;
            const int gc  = (lc ^ (row & 7)) * 8;   // swizzled global k-chunk
            const ushort* gb = W + (size_t)(n0 + row) * K + kt + gc;
            __builtin_amdgcn_global_load_lds((const __attribute__((address_space(1))) void*)gb,
                                             (__attribute__((address_space(3))) void*)&lsB[row * 64 + lc * 8],
                                             16, 0, 0);
            if (!AF32) {
                const ushort* ga = (const ushort*)Av + (size_t)(m0 + row) * lda + kt + gc;
                __builtin_amdgcn_global_load_lds((const __attribute__((address_space(1))) void*)ga,
                                                 (__attribute__((address_space(3))) void*)&lsA[row * 64 + lc * 8],
                                                 16, 0, 0);
            } else {
                const float* ga = (const float*)Av + (size_t)(m0 + row) * lda + kt + gc;
                float4 f0 = *(const float4*)ga;
                float4 f1 = *(const float4*)(ga + 4);
                ushort8v u;
                u[0] = f2bf(f0.x); u[1] = f2bf(f0.y); u[2] = f2bf(f0.z); u[3] = f2bf(f0.w);
                u[4] = f2bf(f1.x); u[5] = f2bf(f1.y); u[6] = f2bf(f1.z); u[7] = f2bf(f1.w);
                *(ushort8v*)&lsA[row * 64 + lc * 8] = u;
            }
        }
        __syncthreads();
        {
            short8 af[4], bfr[4];
#pragma unroll
            for (int i = 0; i < 4; i++) af[i]  = *(const short8*)&lsA[(wm + i * 16 + r16) * 64 + e0];
#pragma unroll
            for (int j = 0; j < 4; j++) bfr[j] = *(const short8*)&lsB[(wn + j * 16 + r16) * 64 + e0];
#pragma unroll
            for (int i = 0; i < 4; i++)
#pragma unroll
                for (int j = 0; j < 4; j++)
                    acc[i][j] = __builtin_amdgcn_mfma_f32_16x16x32_bf16(bfr[j], af[i], acc[i][j], 0, 0, 0);
#pragma unroll
            for (int i = 0; i < 4; i++) af[i]  = *(const short8*)&lsA[(wm + i * 16 + r16) * 64 + e1];
#pragma unroll
            for (int j = 0; j < 4; j++) bfr[j] = *(const short8*)&lsB[(wn + j * 16 + r16) * 64 + e1];
#pragma unroll
            for (int i = 0; i < 4; i++)
#pragma unroll
                for (int j = 0; j < 4; j++)
                    acc[i][j] = __builtin_amdgcn_mfma_f32_16x16x32_bf16(bfr[j], af[i], acc[i][j], 0, 0, 0);
        }
    }

    // transposed C-layout: lane holds row = (tile base + r16), cols = j*16 + q*4 + [0..3]
#pragma unroll
    for (int j = 0; j < 4; j++) {
        const int col = n0 + wn + j * 16 + q * 4;
        const float4 bv = *(const float4*)(bias + col);
#pragma unroll
        for (int i = 0; i < 4; i++) {
            const int row = m0 + wm + i * 16 + r16;
            float v0 = acc[i][j][0] + bv.x;
            float v1 = acc[i][j][1] + bv.y;
            float v2 = acc[i][j][2] + bv.z;
            float v3 = acc[i][j][3] + bv.w;
            if (ACT == 1) { v0 = gelu_f(v0); v1 = gelu_f(v1); v2 = gelu_f(v2); v3 = gelu_f(v3); }
            store4(&C[(size_t)row * ldc + col], v0, v1, v2, v3);
        }
    }
}

// 1D grid of nx*ny blocks, XCD-band swizzled (bh = ny/8)
template<int ACT, typename TOUT>
__global__ __launch_bounds__(256, 4) void gemm_bt(const ushort* __restrict__ A, int lda,
                                                  const ushort* __restrict__ W,
                                                  const float* __restrict__ bias,
                                                  TOUT* __restrict__ C, int ldc, int K,
                                                  int bh) {
    int2 xy = swz_xy(blockIdx.x, bh);
    gemm_core<ACT, 0, TOUT>(A, lda, W, bias, C, ldc, K, xy.y * 128, xy.x * 128);
}

// both embed GEMMs in one dispatch; A read as fp32 and converted in staging
__global__ __launch_bounds__(256, 3) void embed_gemm(const float* __restrict__ A0,
                                                     const float* __restrict__ A1,
                                                     const ushort* __restrict__ W0,
                                                     const ushort* __restrict__ W1,
                                                     const float* __restrict__ b0,
                                                     const float* __restrict__ b1,
                                                     ushort* __restrict__ C) {
    const int z = blockIdx.z;
    int2 xy = swz_xy(blockIdx.x, 8);   // ny=64 -> bh=8
    gemm_core<0, 1, ushort>(z ? (const void*)A1 : (const void*)A0, 512,
                            z ? W1 : W0, z ? b1 : b0,
                            C + z * 1024, 2048, 512,
                            xy.y * 128, xy.x * 128);
}

// ---------- LayerNorm in place over rows of combined (16384 x 1024 bf16) ----------
__global__ __launch_bounds__(256) void ln_kernel(ushort* __restrict__ comb,
                                                 const float* __restrict__ g1, const float* __restrict__ b1,
                                                 const float* __restrict__ g2, const float* __restrict__ b2) {
    int row = blockIdx.x;
    int s = row & 1;
    const float* g = s ? g2 : g1;
    const float* bb = s ? b2 : b1;
    ushort* p = comb + (size_t)row * 1024;
    int t = threadIdx.x;
    ushort4 u = *(const ushort4*)(p + t * 4);
    float x0 = bf2f(u.x), x1 = bf2f(u.y), x2 = bf2f(u.z), x3 = bf2f(u.w);
    float sum = x0 + x1 + x2 + x3;
    float ss = x0 * x0 + x1 * x1 + x2 * x2 + x3 * x3;
#pragma unroll
    for (int off = 32; off; off >>= 1) {
        sum += __shfl_xor(sum, off);
        ss  += __shfl_xor(ss, off);
    }
    __shared__ float sm[8];
    int wv = t >> 6, l = t & 63;
    if (l == 0) { sm[wv * 2] = sum; sm[wv * 2 + 1] = ss; }
    __syncthreads();
    sum = sm[0] + sm[2] + sm[4] + sm[6];
    ss  = sm[1] + sm[3] + sm[5] + sm[7];
    float mean = sum * (1.0f / 1024.0f);
    float var  = ss * (1.0f / 1024.0f) - mean * mean;
    float rstd = rsqrtf(var + 1e-5f);
    float4 gv = *(const float4*)(g + t * 4);
    float4 bv = *(const float4*)(bb + t * 4);
    ushort4 o;
    o.x = f2bf((x0 - mean) * rstd * gv.x + bv.x);
    o.y = f2bf((x1 - mean) * rstd * gv.y + bv.y);
    o.z = f2bf((x2 - mean) * rstd * gv.z + bv.z);
    o.w = f2bf((x3 - mean) * rstd * gv.w + bv.w);
    *(ushort4*)(p + t * 4) = o;
}

// ---------- attention v2 (R4): one block per pair; LDS-staged; compact O ----------
__global__ __launch_bounds__(256) void attn_kernel(const ushort* __restrict__ qkv,
                                                   ushort* __restrict__ O) {
    __shared__ ushort ls[6144];
    const int b = blockIdx.x;
    const int t = threadIdx.x;
    const ushort* src = qkv + (size_t)b * 6144;
#pragma unroll
    for (int p = 0; p < 3; ++p) {
        int idx = (p * 256 + t) * 8;
        *(ushort8v*)&ls[idx] = *(const ushort8v*)&src[idx];
    }
    __syncthreads();
    const int h = t >> 5, d32 = t & 31;
    const int o0 = h * 128 + d32 * 4;
    ushort4 uq0 = *(const ushort4*)&ls[o0];
    ushort4 uq1 = *(const ushort4*)&ls[3072 + o0];
    ushort4 uk0 = *(const ushort4*)&ls[1024 + o0];
    ushort4 uk1 = *(const ushort4*)&ls[4096 + o0];
    ushort4 uv0 = *(const ushort4*)&ls[2048 + o0];
    ushort4 uv1 = *(const ushort4*)&ls[5120 + o0];
    float q0[4] = {bf2f(uq0.x), bf2f(uq0.y), bf2f(uq0.z), bf2f(uq0.w)};
    float q1[4] = {bf2f(uq1.x), bf2f(uq1.y), bf2f(uq1.z), bf2f(uq1.w)};
    float k0[4] = {bf2f(uk0.x), bf2f(uk0.y), bf2f(uk0.z), bf2f(uk0.w)};
    float k1[4] = {bf2f(uk1.x), bf2f(uk1.y), bf2f(uk1.z), bf2f(uk1.w)};
    float v0[4] = {bf2f(uv0.x), bf2f(uv0.y), bf2f(uv0.z), bf2f(uv0.w)};
    float v1[4] = {bf2f(uv1.x), bf2f(uv1.y), bf2f(uv1.z), bf2f(uv1.w)};
    float p00 = 0.f, p01 = 0.f, p10 = 0.f, p11 = 0.f;
#pragma unroll
    for (int i = 0; i < 4; i++) {
        p00 += q0[i] * k0[i];
        p01 += q0[i] * k1[i];
        p10 += q1[i] * k0[i];
        p11 += q1[i] * k1[i];
    }
#pragma unroll
    for (int off = 16; off; off >>= 1) {
        p00 += __shfl_xor(p00, off);
        p01 += __shfl_xor(p01, off);
        p10 += __shfl_xor(p10, off);
        p11 += __shfl_xor(p11, off);
    }
    const float sc = 0.08838834764831845f;  // 1/sqrt(128)
    p00 *= sc; p01 *= sc; p10 *= sc; p11 *= sc;
    float m0 = fmaxf(p00, p01), m1 = fmaxf(p10, p11);
    float e00 = expf(p00 - m0), e01 = expf(p01 - m0);
    float e10 = expf(p10 - m1), e11 = expf(p11 - m1);
    float i0 = 1.0f / (e00 + e01), i1 = 1.0f / (e10 + e11);
    float a00 = e00 * i0, a01 = e01 * i0;
    float a10 = e10 * i1, a11 = e11 * i1;
    ushort* dst0 = O + (size_t)(b * 2) * 1024 + o0;
    ushort* dst1 = dst0 + 1024;
    store4(dst0, a00 * v0[0] + a01 * v1[0], a00 * v0[1] + a01 * v1[1],
                 a00 * v0[2] + a01 * v1[2], a00 * v0[3] + a01 * v1[3]);
    store4(dst1, a10 * v0[0] + a11 * v1[0], a10 * v0[1] + a11 * v1[1],
                 a10 * v0[2] + a11 * v1[2], a10 * v0[3] + a11 * v1[3]);
}

// ---------- gate2 (dot over 1024 x2) + softmax + fused combine ----------
__global__ __launch_bounds__(256) void gate2_kernel(const ushort* __restrict__ gate_h,
                                                    const float* __restrict__ w2, const float* __restrict__ b2,
                                                    const ushort* __restrict__ attn_out,
                                                    ushort* __restrict__ fused_pre,
                                                    float* __restrict__ gw_out) {
    int b = blockIdx.x;
    int t = threadIdx.x;
    const ushort* hp = gate_h + (size_t)b * 1024;
    ushort4 u = *(const ushort4*)(hp + t * 4);
    float4 w0 = *(const float4*)(w2 + t * 4);
    float4 w1 = *(const float4*)(w2 + 1024 + t * 4);
    float h0 = bf2f(u.x), h1 = bf2f(u.y), h2 = bf2f(u.z), h3 = bf2f(u.w);
    float p0 = h0 * w0.x + h1 * w0.y + h2 * w0.z + h3 * w0.w;
    float p1 = h0 * w1.x + h1 * w1.y + h2 * w1.z + h3 * w1.w;
#pragma unroll
    for (int off = 32; off; off >>= 1) {
        p0 += __shfl_xor(p0, off);
        p1 += __shfl_xor(p1, off);
    }
    __shared__ float sm[8];
    __shared__ float sgw[2];
    int wv = t >> 6, l = t & 63;
    if (l == 0) { sm[wv * 2] = p0; sm[wv * 2 + 1] = p1; }
    __syncthreads();
    if (t == 0) {
        float d0 = sm[0] + sm[2] + sm[4] + sm[6] + b2[0];
        float d1 = sm[1] + sm[3] + sm[5] + sm[7] + b2[1];
        float mx = fmaxf(d0, d1);
        float e0 = expf(d0 - mx), e1 = expf(d1 - mx);
        float inv = 1.0f / (e0 + e1);
        sgw[0] = e0 * inv; sgw[1] = e1 * inv;
        gw_out[b * 2] = e0 * inv;
        gw_out[b * 2 + 1] = e1 * inv;
    }
    __syncthreads();
    float g0 = sgw[0], g1 = sgw[1];
    const ushort* ca = attn_out + (size_t)b * 2048;
    ushort* fp = fused_pre + (size_t)b * 1024;
    ushort4 uc = *(const ushort4*)(ca + t * 4);
    ushort4 ug = *(const ushort4*)(ca + 1024 + t * 4);
    ushort4 o;
    o.x = f2bf(g0 * bf2f(uc.x) + g1 * bf2f(ug.x));
    o.y = f2bf(g0 * bf2f(uc.y) + g1 * bf2f(ug.y));
    o.z = f2bf(g0 * bf2f(uc.z) + g1 * bf2f(ug.z));
    o.w = f2bf(g0 * bf2f(uc.w) + g1 * bf2f(ug.w));
    *(ushort4*)(fp + t * 4) = o;
}

// ---------- workspace layout (bytes) ----------
// OFF_COMB region is time-multiplexed: comb -> O -> gate_h / fused_pre
#define OFF_W_CNN  16777216u
#define OFF_W_GNN  17825792u
#define OFF_W_QKV  18874368u
#define OFF_W_AO   25165824u
#define OFF_W_G1   27262976u
#define OFF_W_PJ   31457280u
#define OFF_COMB   33554432u
#define OFF_QKV    67108864u   /* 16384x3072 bf16 */
#define OFF_AO     167772160u  /* 16384x1024 bf16 == gate_in (8192 x 2048) */

extern "C" void kernel_launch(void* const* d_in, const int* in_sizes, int n_in,
                              void* d_out, int out_size, void* d_ws, size_t ws_size,
                              hipStream_t stream) {
    const float* cnn_embed  = (const float*)d_in[0];
    const float* gnn_embed  = (const float*)d_in[1];
    const float* cnn_w      = (const float*)d_in[2];
    const float* cnn_b      = (const float*)d_in[3];
    const float* gnn_w      = (const float*)d_in[4];
    const float* gnn_b      = (const float*)d_in[5];
    const float* ln1_g      = (const float*)d_in[6];
    const float* ln1_b      = (const float*)d_in[7];
    const float* ln2_g      = (const float*)d_in[8];
    const float* ln2_b      = (const float*)d_in[9];
    const float* attn_in_w  = (const float*)d_in[10];
    const float* attn_in_b  = (const float*)d_in[11];
    const float* attn_out_w = (const float*)d_in[12];
    const float* attn_out_b = (const float*)d_in[13];
    const float* gate_w1    = (const float*)d_in[14];
    const float* gate_b1    = (const float*)d_in[15];
    const float* gate_w2    = (const float*)d_in[16];
    const float* gate_b2    = (const float*)d_in[17];
    const float* proj_w     = (const float*)d_in[18];
    const float* proj_b     = (const float*)d_in[19];

    char* ws = (char*)d_ws;
    ushort* w_cnn  = (ushort*)(ws + OFF_W_CNN);
    ushort* w_gnn  = (ushort*)(ws + OFF_W_GNN);
    ushort* w_qkv  = (ushort*)(ws + OFF_W_QKV);
    ushort* w_ao   = (ushort*)(ws + OFF_W_AO);
    ushort* w_g1   = (ushort*)(ws + OFF_W_G1);
    ushort* w_pj   = (ushort*)(ws + OFF_W_PJ);
    ushort* comb   = (ushort*)(ws + OFF_COMB);
    ushort* qkv    = (ushort*)(ws + OFF_QKV);
    ushort* ao     = (ushort*)(ws + OFF_AO);
    ushort* Obuf      = (ushort*)(ws + OFF_COMB);              // alias: comb dead after qkv GEMM
    ushort* gate_h    = (ushort*)(ws + OFF_COMB);              // alias: O dead after attn_out GEMM
    ushort* fused_pre = (ushort*)(ws + OFF_COMB + 16777216u);

    float* out_f  = (float*)d_out;
    float* gw_out = out_f + 8192 * 1024;

    // ---- weight fp32 -> bf16 converts in one dispatch ----
    CvtDesc cd;
    cd.in[0] = cnn_w;      cd.out[0] = w_cnn; cd.nblk[0] = 512;
    cd.in[1] = gnn_w;      cd.out[1] = w_gnn; cd.nblk[1] = 512;
    cd.in[2] = attn_in_w;  cd.out[2] = w_qkv; cd.nblk[2] = 3072;
    cd.in[3] = attn_out_w; cd.out[3] = w_ao;  cd.nblk[3] = 1024;
    cd.in[4] = gate_w1;    cd.out[4] = w_g1;  cd.nblk[4] = 2048;
    cd.in[5] = proj_w;     cd.out[5] = w_pj;  cd.nblk[5] = 1024;
    cvt_all_kernel<<<8192, 256, 0, stream>>>(cd);

    dim3 blk(256);

    // ---- both embed GEMMs (fp32 A converted in staging) -> combined (B,2,F) ----
    dim3 g_embed(8 * 64, 1, 2);
    embed_gemm<<<g_embed, blk, 0, stream>>>(cnn_embed, gnn_embed, w_cnn, w_gnn, cnn_b, gnn_b, comb);

    // ---- LayerNorm in place ----
    ln_kernel<<<16384, blk, 0, stream>>>(comb, ln1_g, ln1_b, ln2_g, ln2_b);

    // ---- qkv GEMM (nx=24, ny=128, bh=16) ----
    gemm_bt<0, ushort><<<24 * 128, blk, 0, stream>>>(comb, 1024, w_qkv, attn_in_b, qkv, 3072, 1024, 16);

    // ---- attention -> compact O ----
    attn_kernel<<<8192, blk, 0, stream>>>(qkv, Obuf);

    // ---- attn_out GEMM (nx=8, ny=128, bh=16) ----
    gemm_bt<0, ushort><<<8 * 128, blk, 0, stream>>>(Obuf, 1024, w_ao, attn_out_b, ao, 1024, 1024, 16);

    // ---- gate1 GEMM (gelu) (nx=8, ny=64, bh=8) ----
    gemm_bt<1, ushort><<<8 * 64, blk, 0, stream>>>(ao, 2048, w_g1, gate_b1, gate_h, 1024, 2048, 8);

    // ---- gate2 + softmax + fused combine ----
    gate2_kernel<<<8192, blk, 0, stream>>>(gate_h, gate_w2, gate_b2, ao, fused_pre, gw_out);

    // ---- proj GEMM (gelu) -> out (nx=8, ny=64, bh=8) ----
    gemm_bt<1, float><<<8 * 64, blk, 0, stream>>>(fused_pre, 1024, w_pj, proj_b, out_f, 1024, 1024, 8);
}